// Round 17
// baseline (187.445 us; speedup 1.0000x reference)
//
#include <hip/hip_runtime.h>

#define NN 50000
#define NE 1600000
#define DD 128
#define HH 128
#define CC 10
#define GG 512
#define LRELU_A 0.05f
#define BN_EPS 1e-5f

#define TT 256          // edge tiles
#define EPT (NE / TT)   // 6250 edges per tile
#define NBR 782         // real src buckets (64 consecutive nodes each)
#define NBP 784         // padded bucket count
#define NPB 64          // nodes per bucket
#define EMAX 2560       // max edges per bucket (mean 2046, +11 sigma)
#define KNODE 8         // nodes per wave in aggregate
#define STB 1024        // stats blocks

typedef unsigned int u32;
typedef unsigned short u16;
typedef unsigned char u8;
typedef __attribute__((ext_vector_type(8))) short bf16x8;
typedef __attribute__((ext_vector_type(4))) float f32x4;

__device__ __forceinline__ u16 f2bf(float f) {
    u32 u = __float_as_uint(f);
    u32 r = u + 0x7FFFu + ((u >> 16) & 1u);
    return (u16)(r >> 16);
}
__device__ __forceinline__ float bf2f(u32 lo16) {  // arg: bf16 in low 16 bits
    return __uint_as_float(lo16 << 16);
}

// ---- k_front: blocks 0..255 = per-tile bucket sort into stage (tile-local
//      25 KB window, L2-friendly); blocks 256..1279 = x stats partials ----
__global__ __launch_bounds__(256) void k_front(const int* __restrict__ src,
                                               const int* __restrict__ dst,
                                               const float* __restrict__ x,
                                               u16* __restrict__ cnt_b,
                                               u16* __restrict__ tpg,
                                               u32* __restrict__ stage,
                                               float* __restrict__ pooled,
                                               double* __restrict__ pst) {
    __shared__ u32 h[NBP];
    __shared__ int tpl[NBP];
    __shared__ int sm2[256];
    __shared__ int carry;
    __shared__ double ls[4], lss[4];
    int bid = blockIdx.x, tid = threadIdx.x;
    if (bid < TT) {
        for (int i = tid; i < NBP; i += 256) h[i] = 0;
        pooled[bid * 256 + tid] = 0.f;   // GG*HH == 256*256
        if (tid == 0) carry = 0;
        __syncthreads();
        int e0 = bid * EPT;
        int s[25]; int rk[25];
        #pragma unroll
        for (int i = 0; i < 25; ++i) {
            int e = i * 256 + tid;
            if (e < EPT) {
                s[i] = src[e0 + e];
                rk[i] = (int)atomicAdd(&h[s[i] >> 6], 1u);
            } else s[i] = -1;
        }
        __syncthreads();
        // counts -> global (for k_mid's base_b scan and k_bcsr)
        for (int i = tid; i < NBP; i += 256) cnt_b[bid * NBP + i] = (u16)h[i];
        // exclusive scan of h over 784 buckets -> tpl
        for (int c = 0; c < 4; ++c) {
            int b = c * 256 + tid;
            int v = (b < NBP) ? (int)h[b] : 0;
            sm2[tid] = v;
            __syncthreads();
            for (int d = 1; d < 256; d <<= 1) {
                int xv = 0;
                if (tid >= d) xv = sm2[tid - d];
                __syncthreads();
                if (tid >= d) sm2[tid] += xv;
                __syncthreads();
            }
            if (b < NBP) tpl[b] = carry + sm2[tid] - v;
            __syncthreads();
            if (tid == 255) carry += sm2[255];
            __syncthreads();
        }
        for (int i = tid; i < NBP; i += 256) tpg[bid * NBP + i] = (u16)tpl[i];
        // scatter edges into the tile-local window of stage
        #pragma unroll
        for (int i = 0; i < 25; ++i) {
            int e = i * 256 + tid;
            if (e < EPT) {
                int b = s[i] >> 6;
                int pos = tpl[b] + rk[i];
                stage[e0 + pos] = ((u32)dst[e0 + e] << 6) | (u32)(s[i] & 63);
            }
        }
    } else {
        int sb = bid - TT;
        const int M4 = NN * DD / 4;
        double sd = 0.0, ssd = 0.0;
        for (int i = sb * 256 + tid; i < M4; i += STB * 256) {
            float4 v = reinterpret_cast<const float4*>(x)[i];
            sd  += (double)v.x + (double)v.y + (double)v.z + (double)v.w;
            ssd += (double)v.x * v.x + (double)v.y * v.y + (double)v.z * v.z +
                   (double)v.w * v.w;
        }
        for (int d = 32; d; d >>= 1) { sd += __shfl_down(sd, d); ssd += __shfl_down(ssd, d); }
        int lane = tid & 63, w = tid >> 6;
        if (lane == 0) { ls[w] = sd; lss[w] = ssd; }
        __syncthreads();
        if (tid == 0) {
            pst[2 * sb]     = ls[0] + ls[1] + ls[2] + ls[3];
            pst[2 * sb + 1] = lss[0] + lss[1] + lss[2] + lss[3];
        }
    }
}

// ---- k_mid (2 blocks): block 0 = base_b scan; block 1 = stats/wsum/wbf ----
__global__ __launch_bounds__(256) void k_mid(const u16* __restrict__ cnt_b,
                                             const double* __restrict__ pst,
                                             const float* __restrict__ fc_w,
                                             int* __restrict__ base_b,
                                             float* __restrict__ wsum,
                                             float* __restrict__ musig,
                                             u16* __restrict__ wbf) {
    int t = threadIdx.x;
    if (blockIdx.x == 0) {
        __shared__ int sm[256];
        __shared__ int runs;
        if (t == 0) runs = 0;
        __syncthreads();
        for (int chunk = 0; chunk < 4; ++chunk) {
            int b = chunk * 256 + t;
            int tot = 0;
            if (b < NBP)
                for (int tt = 0; tt < TT; ++tt) tot += cnt_b[tt * NBP + b];
            sm[t] = tot;
            __syncthreads();
            for (int d = 1; d < 256; d <<= 1) {
                int x = 0;
                if (t >= d) x = sm[t - d];
                __syncthreads();
                if (t >= d) sm[t] += x;
                __syncthreads();
            }
            if (b < NBP) base_b[b] = runs + sm[t] - tot;
            __syncthreads();
            if (t == 255) runs += sm[255];
            __syncthreads();
        }
        if (t == 0) base_b[NBP] = runs;  // == NE
    } else {
        __shared__ double rs[256], rss[256];
        double s  = pst[2 * t] + pst[2 * (t + 256)] + pst[2 * (t + 512)] + pst[2 * (t + 768)];
        double ss = pst[2 * t + 1] + pst[2 * (t + 256) + 1] +
                    pst[2 * (t + 512) + 1] + pst[2 * (t + 768) + 1];
        rs[t] = s; rss[t] = ss;
        __syncthreads();
        for (int d = 128; d; d >>= 1) {
            if (t < d) { rs[t] += rs[t + d]; rss[t] += rss[t + d]; }
            __syncthreads();
        }
        if (t == 0) {
            double M = (double)NN * DD;
            double mean = rs[0] / M;
            double var  = (rss[0] - rs[0] * rs[0] / M) / (M - 1.0);  // ddof=1
            musig[0] = (float)mean;
            musig[1] = (float)(1.0 / sqrt(var));
        }
        for (int i = t; i < DD * HH; i += 256) wbf[i] = f2bf(fc_w[i]);
        if (t < 128) {
            float acc = 0.f;
            for (int k = 0; k < DD; ++k)
                acc += bf2f(f2bf(fc_w[t * DD + k]));
            wsum[t] = acc;
        }
    }
}

// ---- k_big: pure MFMA bf16 gemm (64 rows x 128 cols per block, 4 waves) ----
#define XP 136
__global__ __launch_bounds__(256) void k_big(const float* __restrict__ x,
                                             const u16* __restrict__ wbf,
                                             const float* __restrict__ wsum,
                                             const float* __restrict__ musig,
                                             const float* __restrict__ a1,
                                             const float* __restrict__ a2,
                                             u32* __restrict__ zbf,
                                             float* __restrict__ s1,
                                             float* __restrict__ s2) {
    __shared__ u16 xls[64 * XP];  // 17.4 KB; x tile (bf16), later reused for z
    int bid = blockIdx.x, tid = threadIdx.x;

    int row0 = bid * 64;
    for (int i = tid; i < 64 * 32; i += 256) {
        int r = i >> 5, m = i & 31;
        int gr = row0 + r;
        float4 v = (gr < NN) ? reinterpret_cast<const float4*>(x)[gr * 32 + m]
                             : make_float4(0.f, 0.f, 0.f, 0.f);
        u32 p0 = ((u32)f2bf(v.y) << 16) | f2bf(v.x);
        u32 p1 = ((u32)f2bf(v.w) << 16) | f2bf(v.z);
        *reinterpret_cast<uint2*>(&xls[r * XP + m * 4]) = make_uint2(p0, p1);
    }
    __syncthreads();

    int w = tid >> 6, l = tid & 63;
    int lrow = l & 15, lk = l >> 4;

    bf16x8 af[4];
    #pragma unroll
    for (int kc = 0; kc < 4; ++kc)
        af[kc] = *reinterpret_cast<const bf16x8*>(
            &xls[(w * 16 + lrow) * XP + kc * 32 + lk * 8]);

    f32x4 acc[8];
    #pragma unroll
    for (int nt = 0; nt < 8; ++nt) acc[nt] = (f32x4){0.f, 0.f, 0.f, 0.f};

    #pragma unroll
    for (int nt = 0; nt < 8; ++nt) {
        #pragma unroll
        for (int kc = 0; kc < 4; ++kc) {
            bf16x8 bfr = *reinterpret_cast<const bf16x8*>(
                &wbf[(nt * 16 + lrow) * DD + kc * 32 + lk * 8]);
            acc[nt] = __builtin_amdgcn_mfma_f32_16x16x32_bf16(af[kc], bfr,
                                                              acc[nt], 0, 0, 0);
        }
    }
    __syncthreads();

    float mu = musig[0], isig = musig[1];
    #pragma unroll
    for (int nt = 0; nt < 8; ++nt) {
        int col = nt * 16 + lrow;
        float wsc = wsum[col];
        #pragma unroll
        for (int r = 0; r < 4; ++r) {
            int lr = w * 16 + lk * 4 + r;   // C/D: row=(lane>>4)*4+r, col=lane&15
            float z = (acc[nt][r] - mu * wsc) * isig;
            xls[lr * XP + col] = f2bf(z);
        }
    }
    __syncthreads();

    {
        int r = tid >> 2, q = tid & 3;
        int gr = row0 + r;
        const uint4* lz = reinterpret_cast<const uint4*>(&xls[r * XP + q * 32]);
        uint4 c0 = lz[0], c1 = lz[1], c2 = lz[2], c3 = lz[3];
        if (gr < NN) {
            uint4* zb = reinterpret_cast<uint4*>(zbf) + gr * 16 + q * 4;
            zb[0] = c0; zb[1] = c1; zb[2] = c2; zb[3] = c3;
        }
        u32 wd[16] = {c0.x, c0.y, c0.z, c0.w, c1.x, c1.y, c1.z, c1.w,
                      c2.x, c2.y, c2.z, c2.w, c3.x, c3.y, c3.z, c3.w};
        const float4* A14 = reinterpret_cast<const float4*>(a1 + q * 32);
        const float4* A24 = reinterpret_cast<const float4*>(a2 + q * 32);
        float p1 = 0.f, p2 = 0.f;
        #pragma unroll
        for (int j = 0; j < 8; ++j) {
            float4 va1 = A14[j], va2 = A24[j];
            u32 wlo = wd[2 * j], whi = wd[2 * j + 1];
            float z0 = bf2f(wlo & 0xFFFFu), z1 = bf2f(wlo >> 16);
            float z2 = bf2f(whi & 0xFFFFu), z3 = bf2f(whi >> 16);
            p1 += z0 * va1.x + z1 * va1.y + z2 * va1.z + z3 * va1.w;
            p2 += z0 * va2.x + z1 * va2.y + z2 * va2.z + z3 * va2.w;
        }
        p1 += __shfl_down(p1, 2, 4); p1 += __shfl_down(p1, 1, 4);
        p2 += __shfl_down(p2, 2, 4); p2 += __shfl_down(p2, 1, 4);
        if (q == 0 && gr < NN) { s1[gr] = p1; s2[gr] = p2; }
    }
}

// ---- k_bcsr: gather bucket's 256 tile-runs from stage into LDS, then
//      per-bucket counting sort -> off[]; emits packed (dst<<16)|h_bf16 ----
__global__ __launch_bounds__(256) void k_bcsr(const u32* __restrict__ stage,
                                              const u16* __restrict__ cnt_b,
                                              const u16* __restrict__ tpg,
                                              const int* __restrict__ base_b,
                                              const float* __restrict__ s1,
                                              const float* __restrict__ s2,
                                              int* __restrict__ off,
                                              u32* __restrict__ dst_s) {
    __shared__ u32 eloc[EMAX];
    __shared__ u32 hist[NPB];
    __shared__ u32 cur[NPB];
    __shared__ int sm[256];
    int b = blockIdx.x, tid = threadIdx.x;
    int ebase = base_b[b];
    int m = base_b[b + 1] - ebase;

    // thread tid = tile tid: copy its run into eloc at the rel-prefix position
    int c_t = (int)cnt_b[tid * NBP + b];
    int tp0 = (int)tpg[tid * NBP + b];
    sm[tid] = c_t;
    __syncthreads();
    for (int d = 1; d < 256; d <<= 1) {
        int x = 0;
        if (tid >= d) x = sm[tid - d];
        __syncthreads();
        if (tid >= d) sm[tid] += x;
        __syncthreads();
    }
    int rel = sm[tid] - c_t;
    const u32* srun = stage + tid * EPT + tp0;
    for (int r = 0; r < c_t; ++r) eloc[rel + r] = srun[r];
    if (tid < NPB) hist[tid] = 0;
    __syncthreads();

    for (int i = tid; i < m; i += 256)
        atomicAdd(&hist[eloc[i] & 63u], 1u);
    __syncthreads();
    if (tid < NPB) sm[tid] = (int)hist[tid];
    __syncthreads();
    for (int d = 1; d < NPB; d <<= 1) {
        int x = 0;
        if (tid < NPB && tid >= d) x = sm[tid - d];
        __syncthreads();
        if (tid < NPB && tid >= d) sm[tid] += x;
        __syncthreads();
    }
    if (tid < NPB) {
        int v = (int)hist[tid];
        int st = sm[tid] - v;
        cur[tid] = (u32)st;
        int n = b * NPB + tid;
        if (n < NN) off[n] = ebase + st;
    }
    if (b == NBR - 1 && tid == 0) off[NN] = NE;
    __syncthreads();
    for (int i = tid; i < m; i += 256) {
        u32 e = eloc[i];
        int ls = (int)(e & 63u);
        int dn = (int)(e >> 6);
        int p = (int)atomicAdd(&cur[ls], 1u);
        float ev = s1[b * NPB + ls] + s2[dn];
        ev = (ev >= 0.f) ? ev : LRELU_A * ev;
        float h = __expf(ev);
        dst_s[ebase + p] = ((u32)dn << 16) | (u32)f2bf(h);
    }
}

// ---- aggregate (r12 version): packed (dst|h) edges, shuffle broadcast,
//      8-deep batched gathers, register pool ----
__global__ __launch_bounds__(256) void k_aggregate(const u32* __restrict__ zbf,
                                                   const int* __restrict__ off,
                                                   const u32* __restrict__ dst_s,
                                                   const int* __restrict__ idx,
                                                   float* __restrict__ pooled) {
    int wave = (blockIdx.x * 256 + threadIdx.x) >> 6;
    int lane = threadIdx.x & 63;
    int n0 = wave * KNODE;
    if (n0 >= NN) return;
    int n1 = n0 + KNODE;
    if (n1 > NN) n1 = NN;

    float pool0 = 0.f, pool1 = 0.f;
    int curg = idx[n0];

    for (int node = n0; node < n1; ++node) {
        int g = idx[node];
        if (g != curg) {
            atomicAdd(&pooled[curg * HH + lane * 2], pool0);
            atomicAdd(&pooled[curg * HH + lane * 2 + 1], pool1);
            pool0 = 0.f; pool1 = 0.f;
            curg = g;
        }
        int j0 = off[node], j1 = off[node + 1];
        float acc0 = 0.f, acc1 = 0.f, hsl = 0.f;

        for (int b = j0; b < j1; b += 64) {
            int cnt = j1 - b;
            if (cnt > 64) cnt = 64;
            int jj = b + ((lane < cnt) ? lane : 0);
            int ul = (int)dst_s[jj];
            if (lane < cnt) hsl += __uint_as_float((u32)ul << 16);
            int k = 0;
            for (; k + 8 <= cnt; k += 8) {
                int eu[8]; u32 uu[8];
                #pragma unroll
                for (int q = 0; q < 8; ++q) eu[q] = __shfl(ul, k + q);
                #pragma unroll
                for (int q = 0; q < 8; ++q)
                    uu[q] = zbf[(((u32)eu[q] >> 16) << 6) | lane];
                #pragma unroll
                for (int q = 0; q < 8; ++q) {
                    float hq = __uint_as_float((u32)eu[q] << 16);
                    acc0 += hq * __uint_as_float(uu[q] << 16);
                    acc1 += hq * __uint_as_float(uu[q] & 0xFFFF0000u);
                }
            }
            for (; k + 4 <= cnt; k += 4) {
                int eu[4]; u32 uu[4];
                #pragma unroll
                for (int q = 0; q < 4; ++q) eu[q] = __shfl(ul, k + q);
                #pragma unroll
                for (int q = 0; q < 4; ++q)
                    uu[q] = zbf[(((u32)eu[q] >> 16) << 6) | lane];
                #pragma unroll
                for (int q = 0; q < 4; ++q) {
                    float hq = __uint_as_float((u32)eu[q] << 16);
                    acc0 += hq * __uint_as_float(uu[q] << 16);
                    acc1 += hq * __uint_as_float(uu[q] & 0xFFFF0000u);
                }
            }
            for (; k < cnt; ++k) {
                int e = __shfl(ul, k);
                float hk = __uint_as_float((u32)e << 16);
                u32 u = zbf[(((u32)e >> 16) << 6) | lane];
                acc0 += hk * __uint_as_float(u << 16);
                acc1 += hk * __uint_as_float(u & 0xFFFF0000u);
            }
        }
        float hs = hsl;
        #pragma unroll
        for (int d = 32; d; d >>= 1) hs += __shfl_xor(hs, d);
        float inv = (hs > 0.f) ? 1.f / hs : 0.f;
        pool0 += fmaxf(acc0 * inv, 0.f);
        pool1 += fmaxf(acc1 * inv, 0.f);
    }
    atomicAdd(&pooled[curg * HH + lane * 2], pool0);
    atomicAdd(&pooled[curg * HH + lane * 2 + 1], pool1);
}

// ---- head: per-block BN stats (pooled is L2-hot) -> fc1 -> fc2 -> log_softmax ----
__global__ __launch_bounds__(128) void k_head(const float* __restrict__ pooled,
                                              const float* __restrict__ gamma,
                                              const float* __restrict__ beta,
                                              const float* __restrict__ fc1w,
                                              const float* __restrict__ fc1b,
                                              const float* __restrict__ fc2w,
                                              const float* __restrict__ fc2b,
                                              float* __restrict__ out) {
    __shared__ __align__(16) float xb[128];
    __shared__ __align__(16) float h1[128];
    __shared__ float lg[16];
    int g = blockIdx.x;
    int t = threadIdx.x;
    float s = 0.f, ss = 0.f;
    #pragma unroll 8
    for (int q = 0; q < GG; ++q) {
        float v = pooled[q * HH + t];
        s += v;
        ss += v * v;
    }
    float mean = s / GG;
    float var  = ss / GG - mean * mean;  // biased
    float sc = gamma[t] * rsqrtf(var + BN_EPS);
    xb[t] = pooled[g * HH + t] * sc + (beta[t] - mean * sc);
    __syncthreads();
    float acc = 0.f;
    const float4* wr = reinterpret_cast<const float4*>(&fc1w[t * HH]);
    #pragma unroll 8
    for (int k = 0; k < 32; ++k) {
        float4 w4 = wr[k];
        float4 xv = *reinterpret_cast<const float4*>(&xb[k * 4]);
        acc += w4.x * xv.x + w4.y * xv.y + w4.z * xv.z + w4.w * xv.w;
    }
    acc += fc1b[t];
    h1[t] = (acc > 0.f) ? acc : 0.f;
    __syncthreads();
    if (t < CC) {
        float a = 0.f;
        const float4* w2 = reinterpret_cast<const float4*>(&fc2w[t * HH]);
        #pragma unroll 8
        for (int k = 0; k < 32; ++k) {
            float4 w4 = w2[k];
            float4 hv = *reinterpret_cast<const float4*>(&h1[k * 4]);
            a += w4.x * hv.x + w4.y * hv.y + w4.z * hv.z + w4.w * hv.w;
        }
        lg[t] = a + fc2b[t];
    }
    __syncthreads();
    if (t == 0) {
        float mx = lg[0];
        for (int c = 1; c < CC; ++c) mx = fmaxf(mx, lg[c]);
        float se = 0.f;
        for (int c = 0; c < CC; ++c) se += __expf(lg[c] - mx);
        float lse = mx + logf(se);
        for (int c = 0; c < CC; ++c) out[g * CC + c] = lg[c] - lse;
    }
}

// ---------------- launch ----------------
extern "C" void kernel_launch(void* const* d_in, const int* in_sizes, int n_in,
                              void* d_out, int out_size, void* d_ws, size_t ws_size,
                              hipStream_t stream) {
    const float* x_in  = (const float*)d_in[0];
    const int*   eidx  = (const int*)d_in[1];
    const int*   src   = eidx;
    const int*   dst   = eidx + NE;
    const int*   idx   = (const int*)d_in[2];
    const float* fc_w  = (const float*)d_in[3];
    const float* a1    = (const float*)d_in[4];
    const float* a2    = (const float*)d_in[5];
    const float* fc1w  = (const float*)d_in[6];
    const float* fc1b  = (const float*)d_in[7];
    const float* fc2w  = (const float*)d_in[8];
    const float* fc2b  = (const float*)d_in[9];
    const float* gamma = (const float*)d_in[10];
    const float* beta  = (const float*)d_in[11];
    float* out = (float*)d_out;

    char* p = (char*)d_ws;
    auto alloc = [&](size_t bytes) {
        char* r = p;
        p += (bytes + 255) & ~(size_t)255;
        return r;
    };
    double* pst    = (double*)alloc((size_t)STB * 2 * sizeof(double));
    float*  wsum   = (float*)alloc(HH * sizeof(float));
    float*  musig  = (float*)alloc(4 * sizeof(float));
    u16*    wbf    = (u16*)alloc((size_t)DD * HH * sizeof(u16));
    u16*    cnt_b  = (u16*)alloc((size_t)TT * NBP * sizeof(u16));
    u16*    tpg    = (u16*)alloc((size_t)TT * NBP * sizeof(u16));
    int*    base_b = (int*)alloc((NBP + 1) * sizeof(int));
    u32*    stage  = (u32*)alloc((size_t)NE * sizeof(u32));
    int*    off    = (int*)alloc((NN + 1) * sizeof(int));
    u32*    dst_s  = (u32*)alloc((size_t)NE * sizeof(u32));
    u32*    zbf    = (u32*)alloc((size_t)NN * (HH / 2) * sizeof(u32));
    float*  s1     = (float*)alloc(NN * sizeof(float));
    float*  s2     = (float*)alloc(NN * sizeof(float));
    float*  pooled = (float*)alloc((size_t)GG * HH * sizeof(float));

    k_front<<<TT + STB, 256, 0, stream>>>(src, dst, x_in, cnt_b, tpg, stage,
                                          pooled, pst);
    k_mid<<<2, 256, 0, stream>>>(cnt_b, pst, fc_w, base_b, wsum, musig, wbf);
    int gemm_blocks = (NN + 63) / 64;  // 782
    k_big<<<gemm_blocks, 256, 0, stream>>>(x_in, wbf, wsum, musig,
                                           a1, a2, zbf, s1, s2);
    k_bcsr<<<NBR, 256, 0, stream>>>(stage, cnt_b, tpg, base_b, s1, s2, off, dst_s);
    int nwaves = (NN + KNODE - 1) / KNODE;          // 6250
    int nblocks = (nwaves + 3) / 4;                 // 4 waves per 256-thr block
    k_aggregate<<<nblocks, 256, 0, stream>>>(zbf, off, dst_s, idx, pooled);
    k_head<<<GG, 128, 0, stream>>>(pooled, gamma, beta, fc1w, fc1b, fc2w, fc2b, out);
}

// Round 19
// 171.422 us; speedup vs baseline: 1.0935x; 1.0935x over previous
//
#include <hip/hip_runtime.h>

#define NN 50000
#define NE 1600000
#define DD 128
#define HH 128
#define CC 10
#define GG 512
#define LRELU_A 0.05f
#define BN_EPS 1e-5f

#define TT 256          // edge tiles
#define EPT (NE / TT)   // 6250 edges per tile
#define NB 196          // src buckets (256 consecutive nodes each)
#define NPB 256         // nodes per bucket
#define KNODE 8         // nodes per wave in aggregate
#define STB 1024        // stats blocks

typedef unsigned int u32;
typedef unsigned short u16;
typedef unsigned char u8;
typedef __attribute__((ext_vector_type(8))) short bf16x8;
typedef __attribute__((ext_vector_type(4))) float f32x4;

__device__ __forceinline__ u16 f2bf(float f) {
    u32 u = __float_as_uint(f);
    u32 r = u + 0x7FFFu + ((u >> 16) & 1u);
    return (u16)(r >> 16);
}
__device__ __forceinline__ float bf2f(u32 lo16) {  // arg: bf16 in low 16 bits
    return __uint_as_float(lo16 << 16);
}

// ---- k_front: blocks 0..255 = bucket histogram + rank + zero pooled;
//               blocks 256..1279 = x stats partials (no atomics) ----
__global__ __launch_bounds__(256) void k_front(const int* __restrict__ src,
                                               const float* __restrict__ x,
                                               u16* __restrict__ cnt_b,
                                               u8* __restrict__ rank_e,
                                               float* __restrict__ pooled,
                                               double* __restrict__ pst) {
    __shared__ u32 h[NB];
    __shared__ double ls[4], lss[4];
    int bid = blockIdx.x, tid = threadIdx.x;
    if (bid < TT) {
        for (int i = tid; i < NB; i += 256) h[i] = 0;
        pooled[bid * 256 + tid] = 0.f;   // GG*HH == 256*256
        __syncthreads();
        int e0 = bid * EPT;
        for (int i = tid; i < EPT; i += 256) {
            int b = src[e0 + i] >> 8;
            u32 old = atomicAdd(&h[b], 1u);
            rank_e[e0 + i] = (u8)old;
        }
        __syncthreads();
        for (int i = tid; i < NB; i += 256) cnt_b[bid * NB + i] = (u16)h[i];
    } else {
        int sb = bid - TT;
        const int M4 = NN * DD / 4;
        double s = 0.0, ss = 0.0;
        for (int i = sb * 256 + tid; i < M4; i += STB * 256) {
            float4 v = reinterpret_cast<const float4*>(x)[i];
            s  += (double)v.x + (double)v.y + (double)v.z + (double)v.w;
            ss += (double)v.x * v.x + (double)v.y * v.y + (double)v.z * v.z +
                  (double)v.w * v.w;
        }
        for (int d = 32; d; d >>= 1) { s += __shfl_down(s, d); ss += __shfl_down(ss, d); }
        int lane = tid & 63, w = tid >> 6;
        if (lane == 0) { ls[w] = s; lss[w] = ss; }
        __syncthreads();
        if (tid == 0) {
            pst[2 * sb]     = ls[0] + ls[1] + ls[2] + ls[3];
            pst[2 * sb + 1] = lss[0] + lss[1] + lss[2] + lss[3];
        }
    }
}

// ---- k_mid (2 blocks): block 0 = brel (tile prefix + bucket bases);
//                        block 1 = stats reduce -> musig, wsum, wbf ----
__global__ __launch_bounds__(256) void k_mid(const u16* __restrict__ cnt_b,
                                             const double* __restrict__ pst,
                                             const float* __restrict__ fc_w,
                                             u16* __restrict__ rel_b,
                                             int* __restrict__ base_b,
                                             float* __restrict__ wsum,
                                             float* __restrict__ musig,
                                             u16* __restrict__ wbf) {
    int t = threadIdx.x;
    if (blockIdx.x == 0) {
        __shared__ int sm[256];
        int b = t;
        int run = 0;
        if (b < NB) {
            for (int tt = 0; tt < TT; ++tt) {
                int c = cnt_b[tt * NB + b];
                rel_b[tt * NB + b] = (u16)run;
                run += c;
            }
        }
        sm[b] = (b < NB) ? run : 0;
        __syncthreads();
        int v = sm[b];
        for (int d = 1; d < 256; d <<= 1) {
            int x = 0;
            if (b >= d) x = sm[b - d];
            __syncthreads();
            if (b >= d) sm[b] += x;
            __syncthreads();
        }
        if (b < NB) base_b[b] = sm[b] - v;
        if (b == NB - 1) base_b[NB] = sm[b];
    } else {
        __shared__ double rs[256], rss[256];
        double s  = pst[2 * t] + pst[2 * (t + 256)] + pst[2 * (t + 512)] + pst[2 * (t + 768)];
        double ss = pst[2 * t + 1] + pst[2 * (t + 256) + 1] +
                    pst[2 * (t + 512) + 1] + pst[2 * (t + 768) + 1];
        rs[t] = s; rss[t] = ss;
        __syncthreads();
        for (int d = 128; d; d >>= 1) {
            if (t < d) { rs[t] += rs[t + d]; rss[t] += rss[t + d]; }
            __syncthreads();
        }
        if (t == 0) {
            double M = (double)NN * DD;
            double mean = rs[0] / M;
            double var  = (rss[0] - rs[0] * rs[0] / M) / (M - 1.0);  // ddof=1
            musig[0] = (float)mean;
            musig[1] = (float)(1.0 / sqrt(var));
        }
        for (int i = t; i < DD * HH; i += 256) wbf[i] = f2bf(fc_w[i]);
        if (t < 128) {
            float acc = 0.f;
            for (int k = 0; k < DD; ++k)
                acc += bf2f(f2bf(fc_w[t * DD + k]));
            wsum[t] = acc;
        }
    }
}

// ---- k_big: blocks 0..255 = bscat; blocks 256..1037 = MFMA bf16 gemm ----
// gemm: 64 rows x 128 cols per block, 4 waves, mfma_f32_16x16x32_bf16.
#define XP 136
__global__ __launch_bounds__(256) void k_big(const int* __restrict__ src,
                                             const int* __restrict__ dst,
                                             const u16* __restrict__ rel_b,
                                             const u8* __restrict__ rank_e,
                                             const int* __restrict__ base_b,
                                             u32* __restrict__ ebuf,
                                             const float* __restrict__ x,
                                             const u16* __restrict__ wbf,
                                             const float* __restrict__ wsum,
                                             const float* __restrict__ musig,
                                             const float* __restrict__ a1,
                                             const float* __restrict__ a2,
                                             u32* __restrict__ zbf,
                                             float* __restrict__ s1,
                                             float* __restrict__ s2) {
    __shared__ u16 xls[64 * XP];  // 17.4 KB
    int bid = blockIdx.x, tid = threadIdx.x;

    if (bid < TT) {
        int e0 = bid * EPT;
        for (int i = tid; i < EPT; i += 256) {
            int s = src[e0 + i];
            int b = s >> 8;
            int pos = base_b[b] + (int)rel_b[bid * NB + b] + (int)rank_e[e0 + i];
            ebuf[pos] = ((u32)dst[e0 + i] << 8) | (u32)(s & 255);
        }
        return;
    }

    int row0 = (bid - TT) * 64;
    for (int i = tid; i < 64 * 32; i += 256) {
        int r = i >> 5, m = i & 31;
        int gr = row0 + r;
        float4 v = (gr < NN) ? reinterpret_cast<const float4*>(x)[gr * 32 + m]
                             : make_float4(0.f, 0.f, 0.f, 0.f);
        u32 p0 = ((u32)f2bf(v.y) << 16) | f2bf(v.x);
        u32 p1 = ((u32)f2bf(v.w) << 16) | f2bf(v.z);
        *reinterpret_cast<uint2*>(&xls[r * XP + m * 4]) = make_uint2(p0, p1);
    }
    __syncthreads();

    int w = tid >> 6, l = tid & 63;
    int lrow = l & 15, lk = l >> 4;

    bf16x8 af[4];
    #pragma unroll
    for (int kc = 0; kc < 4; ++kc)
        af[kc] = *reinterpret_cast<const bf16x8*>(
            &xls[(w * 16 + lrow) * XP + kc * 32 + lk * 8]);

    f32x4 acc[8];
    #pragma unroll
    for (int nt = 0; nt < 8; ++nt) acc[nt] = (f32x4){0.f, 0.f, 0.f, 0.f};

    #pragma unroll
    for (int nt = 0; nt < 8; ++nt) {
        #pragma unroll
        for (int kc = 0; kc < 4; ++kc) {
            bf16x8 bfr = *reinterpret_cast<const bf16x8*>(
                &wbf[(nt * 16 + lrow) * DD + kc * 32 + lk * 8]);
            acc[nt] = __builtin_amdgcn_mfma_f32_16x16x32_bf16(af[kc], bfr,
                                                              acc[nt], 0, 0, 0);
        }
    }
    __syncthreads();

    float mu = musig[0], isig = musig[1];
    #pragma unroll
    for (int nt = 0; nt < 8; ++nt) {
        int col = nt * 16 + lrow;
        float wsc = wsum[col];
        #pragma unroll
        for (int r = 0; r < 4; ++r) {
            int lr = w * 16 + lk * 4 + r;   // C/D: row=(lane>>4)*4+r, col=lane&15
            float z = (acc[nt][r] - mu * wsc) * isig;
            xls[lr * XP + col] = f2bf(z);
        }
    }
    __syncthreads();

    {
        int r = tid >> 2, q = tid & 3;
        int gr = row0 + r;
        const uint4* lz = reinterpret_cast<const uint4*>(&xls[r * XP + q * 32]);
        uint4 c0 = lz[0], c1 = lz[1], c2 = lz[2], c3 = lz[3];
        if (gr < NN) {
            uint4* zb = reinterpret_cast<uint4*>(zbf) + gr * 16 + q * 4;
            zb[0] = c0; zb[1] = c1; zb[2] = c2; zb[3] = c3;
        }
        u32 wd[16] = {c0.x, c0.y, c0.z, c0.w, c1.x, c1.y, c1.z, c1.w,
                      c2.x, c2.y, c2.z, c2.w, c3.x, c3.y, c3.z, c3.w};
        const float4* A14 = reinterpret_cast<const float4*>(a1 + q * 32);
        const float4* A24 = reinterpret_cast<const float4*>(a2 + q * 32);
        float p1 = 0.f, p2 = 0.f;
        #pragma unroll
        for (int j = 0; j < 8; ++j) {
            float4 va1 = A14[j], va2 = A24[j];
            u32 wlo = wd[2 * j], whi = wd[2 * j + 1];
            float z0 = bf2f(wlo & 0xFFFFu), z1 = bf2f(wlo >> 16);
            float z2 = bf2f(whi & 0xFFFFu), z3 = bf2f(whi >> 16);
            p1 += z0 * va1.x + z1 * va1.y + z2 * va1.z + z3 * va1.w;
            p2 += z0 * va2.x + z1 * va2.y + z2 * va2.z + z3 * va2.w;
        }
        p1 += __shfl_down(p1, 2, 4); p1 += __shfl_down(p1, 1, 4);
        p2 += __shfl_down(p2, 2, 4); p2 += __shfl_down(p2, 1, 4);
        if (q == 0 && gr < NN) { s1[gr] = p1; s2[gr] = p2; }
    }
}

// ---- k_bcsr: per-bucket (256 nodes) counting sort -> off[];
//      emits packed (dst<<16)|h_bf16 ----
__global__ __launch_bounds__(256) void k_bcsr(const u32* __restrict__ ebuf,
                                              const int* __restrict__ base_b,
                                              const float* __restrict__ s1,
                                              const float* __restrict__ s2,
                                              int* __restrict__ off,
                                              u32* __restrict__ dst_s) {
    __shared__ u32 hist[NPB];
    __shared__ u32 cur[NPB];
    __shared__ int sm[256];
    int b = blockIdx.x, tid = threadIdx.x;
    int ebase = base_b[b], eend = base_b[b + 1];
    int m = eend - ebase;
    hist[tid] = 0;
    __syncthreads();
    for (int i = tid; i < m; i += 256)
        atomicAdd(&hist[ebuf[ebase + i] & 255u], 1u);
    __syncthreads();
    int v = (int)hist[tid];
    sm[tid] = v;
    __syncthreads();
    for (int d = 1; d < 256; d <<= 1) {
        int x = 0;
        if (tid >= d) x = sm[tid - d];
        __syncthreads();
        if (tid >= d) sm[tid] += x;
        __syncthreads();
    }
    int st = sm[tid] - v;
    cur[tid] = (u32)st;
    int n = b * NPB + tid;
    if (n < NN) off[n] = ebase + st;
    if (b == NB - 1 && tid == 0) off[NN] = NE;
    __syncthreads();
    for (int i = tid; i < m; i += 256) {
        u32 e = ebuf[ebase + i];
        int ls = (int)(e & 255u);
        int dn = (int)(e >> 8);
        int p = (int)atomicAdd(&cur[ls], 1u);
        float ev = s1[b * NPB + ls] + s2[dn];
        ev = (ev >= 0.f) ? ev : LRELU_A * ev;
        float h = __expf(ev);
        dst_s[ebase + p] = ((u32)dn << 16) | (u32)f2bf(h);
    }
}

// ---- aggregate (r12 version): packed (dst|h) edges, shuffle broadcast,
//      8-deep batched gathers, register pool ----
__global__ __launch_bounds__(256) void k_aggregate(const u32* __restrict__ zbf,
                                                   const int* __restrict__ off,
                                                   const u32* __restrict__ dst_s,
                                                   const int* __restrict__ idx,
                                                   float* __restrict__ pooled) {
    int wave = (blockIdx.x * 256 + threadIdx.x) >> 6;
    int lane = threadIdx.x & 63;
    int n0 = wave * KNODE;
    if (n0 >= NN) return;
    int n1 = n0 + KNODE;
    if (n1 > NN) n1 = NN;

    float pool0 = 0.f, pool1 = 0.f;
    int curg = idx[n0];

    for (int node = n0; node < n1; ++node) {
        int g = idx[node];
        if (g != curg) {
            atomicAdd(&pooled[curg * HH + lane * 2], pool0);
            atomicAdd(&pooled[curg * HH + lane * 2 + 1], pool1);
            pool0 = 0.f; pool1 = 0.f;
            curg = g;
        }
        int j0 = off[node], j1 = off[node + 1];
        float acc0 = 0.f, acc1 = 0.f, hsl = 0.f;

        for (int b = j0; b < j1; b += 64) {
            int cnt = j1 - b;
            if (cnt > 64) cnt = 64;
            int jj = b + ((lane < cnt) ? lane : 0);
            int ul = (int)dst_s[jj];
            if (lane < cnt) hsl += __uint_as_float((u32)ul << 16);
            int k = 0;
            for (; k + 8 <= cnt; k += 8) {
                int eu[8]; u32 uu[8];
                #pragma unroll
                for (int q = 0; q < 8; ++q) eu[q] = __shfl(ul, k + q);
                #pragma unroll
                for (int q = 0; q < 8; ++q)
                    uu[q] = zbf[(((u32)eu[q] >> 16) << 6) | lane];
                #pragma unroll
                for (int q = 0; q < 8; ++q) {
                    float hq = __uint_as_float((u32)eu[q] << 16);
                    acc0 += hq * __uint_as_float(uu[q] << 16);
                    acc1 += hq * __uint_as_float(uu[q] & 0xFFFF0000u);
                }
            }
            for (; k + 4 <= cnt; k += 4) {
                int eu[4]; u32 uu[4];
                #pragma unroll
                for (int q = 0; q < 4; ++q) eu[q] = __shfl(ul, k + q);
                #pragma unroll
                for (int q = 0; q < 4; ++q)
                    uu[q] = zbf[(((u32)eu[q] >> 16) << 6) | lane];
                #pragma unroll
                for (int q = 0; q < 4; ++q) {
                    float hq = __uint_as_float((u32)eu[q] << 16);
                    acc0 += hq * __uint_as_float(uu[q] << 16);
                    acc1 += hq * __uint_as_float(uu[q] & 0xFFFF0000u);
                }
            }
            for (; k < cnt; ++k) {
                int e = __shfl(ul, k);
                float hk = __uint_as_float((u32)e << 16);
                u32 u = zbf[(((u32)e >> 16) << 6) | lane];
                acc0 += hk * __uint_as_float(u << 16);
                acc1 += hk * __uint_as_float(u & 0xFFFF0000u);
            }
        }
        float hs = hsl;
        #pragma unroll
        for (int d = 32; d; d >>= 1) hs += __shfl_xor(hs, d);
        float inv = (hs > 0.f) ? 1.f / hs : 0.f;
        pool0 += fmaxf(acc0 * inv, 0.f);
        pool1 += fmaxf(acc1 * inv, 0.f);
    }
    atomicAdd(&pooled[curg * HH + lane * 2], pool0);
    atomicAdd(&pooled[curg * HH + lane * 2 + 1], pool1);
}

// ---- head: per-block BN stats (pooled is L2-hot) -> fc1 -> fc2 -> log_softmax ----
__global__ __launch_bounds__(128) void k_head(const float* __restrict__ pooled,
                                              const float* __restrict__ gamma,
                                              const float* __restrict__ beta,
                                              const float* __restrict__ fc1w,
                                              const float* __restrict__ fc1b,
                                              const float* __restrict__ fc2w,
                                              const float* __restrict__ fc2b,
                                              float* __restrict__ out) {
    __shared__ __align__(16) float xb[128];
    __shared__ __align__(16) float h1[128];
    __shared__ float lg[16];
    int g = blockIdx.x;
    int t = threadIdx.x;
    float s = 0.f, ss = 0.f;
    #pragma unroll 8
    for (int q = 0; q < GG; ++q) {
        float v = pooled[q * HH + t];
        s += v;
        ss += v * v;
    }
    float mean = s / GG;
    float var  = ss / GG - mean * mean;  // biased
    float sc = gamma[t] * rsqrtf(var + BN_EPS);
    xb[t] = pooled[g * HH + t] * sc + (beta[t] - mean * sc);
    __syncthreads();
    float acc = 0.f;
    const float4* wr = reinterpret_cast<const float4*>(&fc1w[t * HH]);
    #pragma unroll 8
    for (int k = 0; k < 32; ++k) {
        float4 w4 = wr[k];
        float4 xv = *reinterpret_cast<const float4*>(&xb[k * 4]);
        acc += w4.x * xv.x + w4.y * xv.y + w4.z * xv.z + w4.w * xv.w;
    }
    acc += fc1b[t];
    h1[t] = (acc > 0.f) ? acc : 0.f;
    __syncthreads();
    if (t < CC) {
        float a = 0.f;
        const float4* w2 = reinterpret_cast<const float4*>(&fc2w[t * HH]);
        #pragma unroll 8
        for (int k = 0; k < 32; ++k) {
            float4 w4 = w2[k];
            float4 hv = *reinterpret_cast<const float4*>(&h1[k * 4]);
            a += w4.x * hv.x + w4.y * hv.y + w4.z * hv.z + w4.w * hv.w;
        }
        lg[t] = a + fc2b[t];
    }
    __syncthreads();
    if (t == 0) {
        float mx = lg[0];
        for (int c = 1; c < CC; ++c) mx = fmaxf(mx, lg[c]);
        float se = 0.f;
        for (int c = 0; c < CC; ++c) se += __expf(lg[c] - mx);
        float lse = mx + logf(se);
        for (int c = 0; c < CC; ++c) out[g * CC + c] = lg[c] - lse;
    }
}

// ---------------- launch ----------------
extern "C" void kernel_launch(void* const* d_in, const int* in_sizes, int n_in,
                              void* d_out, int out_size, void* d_ws, size_t ws_size,
                              hipStream_t stream) {
    const float* x_in  = (const float*)d_in[0];
    const int*   eidx  = (const int*)d_in[1];
    const int*   src   = eidx;
    const int*   dst   = eidx + NE;
    const int*   idx   = (const int*)d_in[2];
    const float* fc_w  = (const float*)d_in[3];
    const float* a1    = (const float*)d_in[4];
    const float* a2    = (const float*)d_in[5];
    const float* fc1w  = (const float*)d_in[6];
    const float* fc1b  = (const float*)d_in[7];
    const float* fc2w  = (const float*)d_in[8];
    const float* fc2b  = (const float*)d_in[9];
    const float* gamma = (const float*)d_in[10];
    const float* beta  = (const float*)d_in[11];
    float* out = (float*)d_out;

    char* p = (char*)d_ws;
    auto alloc = [&](size_t bytes) {
        char* r = p;
        p += (bytes + 255) & ~(size_t)255;
        return r;
    };
    double* pst    = (double*)alloc((size_t)STB * 2 * sizeof(double));
    float*  wsum   = (float*)alloc(HH * sizeof(float));
    float*  musig  = (float*)alloc(4 * sizeof(float));
    u16*    wbf    = (u16*)alloc((size_t)DD * HH * sizeof(u16));
    u16*    cnt_b  = (u16*)alloc((size_t)TT * NB * sizeof(u16));
    u16*    rel_b  = (u16*)alloc((size_t)TT * NB * sizeof(u16));
    u8*     rank_e = (u8*)alloc((size_t)NE * sizeof(u8));
    int*    base_b = (int*)alloc((NB + 1) * sizeof(int));
    u32*    ebuf   = (u32*)alloc((size_t)NE * sizeof(u32));
    int*    off    = (int*)alloc((NN + 1) * sizeof(int));
    u32*    dst_s  = (u32*)alloc((size_t)NE * sizeof(u32));
    u32*    zbf    = (u32*)alloc((size_t)NN * (HH / 2) * sizeof(u32));
    float*  s1     = (float*)alloc(NN * sizeof(float));
    float*  s2     = (float*)alloc(NN * sizeof(float));
    float*  pooled = (float*)alloc((size_t)GG * HH * sizeof(float));

    k_front<<<TT + STB, 256, 0, stream>>>(src, x_in, cnt_b, rank_e, pooled, pst);
    k_mid<<<2, 256, 0, stream>>>(cnt_b, pst, fc_w, rel_b, base_b, wsum, musig, wbf);
    int gemm_blocks = (NN + 63) / 64;  // 782
    k_big<<<TT + gemm_blocks, 256, 0, stream>>>(src, dst, rel_b, rank_e, base_b,
                                                ebuf, x_in, wbf, wsum, musig,
                                                a1, a2, zbf, s1, s2);
    k_bcsr<<<NB, 256, 0, stream>>>(ebuf, base_b, s1, s2, off, dst_s);
    int nwaves = (NN + KNODE - 1) / KNODE;          // 6250
    int nblocks = (nwaves + 3) / 4;                 // 4 waves per 256-thr block
    k_aggregate<<<nblocks, 256, 0, stream>>>(zbf, off, dst_s, idx, pooled);
    k_head<<<GG, 128, 0, stream>>>(pooled, gamma, beta, fc1w, fc1b, fc2w, fc2b, out);
}